// Round 2
// baseline (240.435 us; speedup 1.0000x reference)
//
#include <hip/hip_runtime.h>
#include <hip/hip_bf16.h>
#include <cstdint>

#define NHQ 16
#define NKVH 4
#define HDIM 128
#define WINSZ 512
#define TSEQ 2048
#define ATTN_SCALE 0.08838834764831845f

typedef __attribute__((ext_vector_type(8))) short s16x8;
typedef __attribute__((ext_vector_type(4))) float f32x4;

__device__ __forceinline__ void gload16(const void* g, void* lds) {
  __builtin_amdgcn_global_load_lds(
      (const __attribute__((address_space(1))) unsigned int*)g,
      (__attribute__((address_space(3))) unsigned int*)(uintptr_t)lds,
      16, 0, 0);
}

__device__ __forceinline__ f32x4 mfma16(s16x8 a, s16x8 b, f32x4 c) {
  return __builtin_amdgcn_mfma_f32_16x16x32_bf16(a, b, c, 0, 0, 0);
}

#define SBAR() asm volatile("s_barrier" ::: "memory")
#define VMCNT(n) asm volatile("s_waitcnt vmcnt(" #n ")" ::: "memory")

// ---------------- rope tables ----------------
__global__ __launch_bounds__(256) void rope_tables_kernel(float* __restrict__ cosT,
                                                          float* __restrict__ sinT) {
  int idx = blockIdx.x * 256 + threadIdx.x;   // t*64 + d2
  int t = idx >> 6, d2 = idx & 63;
  float inv = powf(10000.0f, -(float)d2 / 64.0f);
  float a = (float)t * inv;
  cosT[idx] = cosf(a);
  sinT[idx] = sinf(a);
}

// ---------------- f32 -> bf16 cast ----------------
__global__ __launch_bounds__(256) void cast_kernel(const float* __restrict__ in,
                                                   __bf16* __restrict__ out, int n4) {
  int i = blockIdx.x * 256 + threadIdx.x;
  if (i >= n4) return;
  float4 v = ((const float4*)in)[i];
  union { __bf16 h[4]; uint2 u; } pk;
  pk.h[0] = (__bf16)v.x; pk.h[1] = (__bf16)v.y; pk.h[2] = (__bf16)v.z; pk.h[3] = (__bf16)v.w;
  ((uint2*)out)[i] = pk.u;
}

// ---------------- transpose + cast: in f32 [R][C] -> out bf16 [C][R] ----------------
__global__ __launch_bounds__(256) void transpose_cast(const float* __restrict__ in,
                                                      __bf16* __restrict__ out, int R, int C) {
  __shared__ float tile[32][33];
  int c0 = blockIdx.x * 32, r0 = blockIdx.y * 32;
  int tx = threadIdx.x, ty = threadIdx.y;  // 32 x 8
#pragma unroll
  for (int i = 0; i < 4; i++)
    tile[ty + i * 8][tx] = in[(size_t)(r0 + ty + i * 8) * C + c0 + tx];
  __syncthreads();
#pragma unroll
  for (int i = 0; i < 4; i++)
    out[(size_t)(c0 + ty + i * 8) * R + r0 + tx] = (__bf16)tile[tx][ty + i * 8];
}

// ---------------- 256x256 phase-pipelined bt-GEMM ----------------
// A[M,K] bf16 row-major, Bt[N,K] bf16 row-major.
// BK=32, 3 LDS buffers (96 KiB), counted vmcnt(3), per-phase barriers + setprio.
// MODE 0: C = f32 [M,N] row-major.  MODE 1: scatter bf16 into Q/K/V head-major.
template <int MODE>
__global__ __launch_bounds__(512, 2) void gemm256(const __bf16* __restrict__ A,
                                                  const __bf16* __restrict__ Bt,
                                                  float* __restrict__ Cf,
                                                  __bf16* __restrict__ Qo, __bf16* __restrict__ Ko,
                                                  __bf16* __restrict__ Vo, int M, int N, int K) {
  // Lds[buf][0]=A-tile 256x32 (16KB, halves of 128 rows), Lds[buf][1]=B-tile
  __shared__ __attribute__((aligned(16))) char Lds[3][2][16384];

  const int tid = threadIdx.x;
  const int w = tid >> 6, lane = tid & 63;
  const int wm = w >> 2, wn = w & 3;

  // bijective XCD-aware block swizzle (m204)
  const int nbx = gridDim.x;
  const int nwg = nbx * gridDim.y;
  const int bid = blockIdx.y * nbx + blockIdx.x;
  const int q8 = nwg >> 3, r8 = nwg & 7;
  const int xcd = bid & 7, idx = bid >> 3;
  const int swz = (xcd < r8 ? xcd * (q8 + 1) : r8 * (q8 + 1) + (xcd - r8) * q8) + idx;
  const int bx = swz % nbx, by = swz / nbx;
  const int m0 = by * 256, n0 = bx * 256;

  // staging: thread tid covers (row r_st = tid>>2, 16B chunk tid&3) of a 128-row half.
  // LDS dest is linear; global source is inverse-swizzled (rule #21).
  const int r_st = tid >> 2;
  const int c_src = (tid & 3) ^ ((tid >> 3) & 3);
  const __bf16* gA = A + (size_t)(m0 + r_st) * K + c_src * 8;
  const __bf16* gB = Bt + (size_t)(n0 + r_st) * K + c_src * 8;
  const size_t hOF = (size_t)128 * K;  // half = 128 rows

  auto stA = [&](int t, int h, int b) {
    gload16(gA + h * hOF + t * 32, Lds[b][0] + h * 8192 + w * 1024);
  };
  auto stB = [&](int t, int h, int b) {
    gload16(gB + h * hOF + t * 32, Lds[b][1] + h * 8192 + w * 1024);
  };

  // fragment ds_read offsets (swizzled chunk = (lane>>4) ^ ((r>>1)&3))
  const int swzr = (((lane >> 4) ^ (((lane & 15) >> 1) & 3)) << 4);
  const int aoff = wm * 8192 + (lane & 15) * 64 + swzr;
  const int boff = (wn >> 1) * 8192 + (wn & 1) * 4096 + (lane & 15) * 64 + swzr;

  f32x4 acc[8][4];
  f32x4 zero = {0.f, 0.f, 0.f, 0.f};
#pragma unroll
  for (int i = 0; i < 8; i++)
#pragma unroll
    for (int j = 0; j < 4; j++) acc[i][j] = zero;

  const int NT = K >> 5;

  // prologue: stage halves 0..6 (tile0 full + tile1 A0,A1,B0); wait tile0.
  stA(0, 0, 0); stA(0, 1, 0); stB(0, 0, 0); stB(0, 1, 0);
  stA(1, 0, 1); stA(1, 1, 1); stB(1, 0, 1);
  VMCNT(3);
  SBAR();

  int cur = 0;
  for (int t = 0; t < NT; ++t) {
    int nb1 = cur + 1; if (nb1 == 3) nb1 = 0;
    int nb2 = nb1 + 1; if (nb2 == 3) nb2 = 0;
    const char* bA = Lds[cur][0];
    const char* bB = Lds[cur][1];

    // ---- phase 0: B frags + A frags (mf 0-3), stage t+1:B1, t+2:A0 ----
    s16x8 fb[4], fa[4];
#pragma unroll
    for (int nf = 0; nf < 4; nf++) fb[nf] = *(const s16x8*)(bB + boff + nf * 1024);
#pragma unroll
    for (int mf = 0; mf < 4; mf++) fa[mf] = *(const s16x8*)(bA + aoff + mf * 1024);
    if (t + 1 < NT) stB(t + 1, 1, nb1);
    if (t + 2 < NT) stA(t + 2, 0, nb2);
    SBAR();
    __builtin_amdgcn_s_setprio(1);
#pragma unroll
    for (int mf = 0; mf < 4; mf++)
#pragma unroll
      for (int nf = 0; nf < 4; nf++) acc[mf][nf] = mfma16(fa[mf], fb[nf], acc[mf][nf]);
    __builtin_amdgcn_s_setprio(0);
    SBAR();

    // ---- phase 1: A frags (mf 4-7), stage t+2:A1, t+2:B0 ----
#pragma unroll
    for (int mf = 0; mf < 4; mf++) fa[mf] = *(const s16x8*)(bA + aoff + 4096 + mf * 1024);
    if (t + 2 < NT) { stA(t + 2, 1, nb2); stB(t + 2, 0, nb2); }
    SBAR();
    __builtin_amdgcn_s_setprio(1);
#pragma unroll
    for (int mf = 0; mf < 4; mf++)
#pragma unroll
      for (int nf = 0; nf < 4; nf++) acc[4 + mf][nf] = mfma16(fa[mf], fb[nf], acc[4 + mf][nf]);
    __builtin_amdgcn_s_setprio(0);

    // ---- tile boundary: counted vmcnt (tile t+1 resident; 3 halves of t+2 in flight) ----
    if (t < NT - 2) {
      VMCNT(3);
      SBAR();
    } else if (t == NT - 2) {
      VMCNT(0);
      SBAR();
    }
    cur = nb1;
  }

  // ---- epilogue ----
#pragma unroll
  for (int mf = 0; mf < 8; mf++)
#pragma unroll
    for (int nf = 0; nf < 4; nf++) {
      int rbase = m0 + wm * 128 + mf * 16 + (lane >> 4) * 4;
      int col = n0 + wn * 64 + nf * 16 + (lane & 15);
#pragma unroll
      for (int r = 0; r < 4; r++) {
        int m = rbase + r;
        float v = acc[mf][nf][r];
        if constexpr (MODE == 0) {
          Cf[(size_t)m * N + col] = v;
        } else {
          int b = m >> 11, t = m & 2047;
          __bf16 bv = (__bf16)v;
          if (col < 2048) {
            Qo[(((size_t)(b * NHQ + (col >> 7))) * TSEQ + t) * HDIM + (col & 127)] = bv;
          } else if (col < 2560) {
            int c2 = col - 2048;
            Ko[(((size_t)(b * NKVH + (c2 >> 7))) * TSEQ + t) * HDIM + (c2 & 127)] = bv;
          } else {
            int c2 = col - 2560;
            Vo[(((size_t)(b * NKVH + (c2 >> 7))) * TSEQ + t) * HDIM + (c2 & 127)] = bv;
          }
        }
      }
    }
}

// ---------------- in-place L2 norm + RoPE on Q and K (head-major) ----------------
__global__ __launch_bounds__(256) void normrope(__bf16* __restrict__ Q, __bf16* __restrict__ Kk,
                                                const float* __restrict__ cosT,
                                                const float* __restrict__ sinT) {
  int w = threadIdx.x >> 6, lane = threadIdx.x & 63;
  int row = blockIdx.x / 5;            // b*T + t
  int slot = (blockIdx.x % 5) * 4 + w; // 0..15 Q heads, 16..19 K heads
  int b = row >> 11, t = row & 2047;
  __bf16* p;
  if (slot < 16)
    p = Q + (((size_t)(b * NHQ + slot)) * TSEQ + t) * HDIM;
  else
    p = Kk + (((size_t)(b * NKVH + (slot - 16))) * TSEQ + t) * HDIM;
  float x1 = (float)p[lane], x2 = (float)p[lane + 64];
  float ss = x1 * x1 + x2 * x2;
#pragma unroll
  for (int off = 32; off; off >>= 1) ss += __shfl_xor(ss, off);
  float inv = 1.0f / fmaxf(sqrtf(ss), 1e-12f);
  x1 *= inv;
  x2 *= inv;
  float c = cosT[t * 64 + lane], s = sinT[t * 64 + lane];
  p[lane] = (__bf16)(x1 * c - x2 * s);
  p[lane + 64] = (__bf16)(x2 * c + x1 * s);
}

// ---------------- sliding-window flash attention ----------------
// grid: b*NHQ*(T/64); block 256 (4 waves x 16 q-rows). KV tile = 32.
__global__ __launch_bounds__(256) void attn_kernel(const __bf16* __restrict__ Qf,
                                                   const __bf16* __restrict__ Kf,
                                                   const __bf16* __restrict__ Vf,
                                                   __bf16* __restrict__ Ab) {
  __shared__ __align__(16) __bf16 Kl[32 * 136];   // padded: row stride 136 elems (272B)
  __shared__ __align__(16) __bf16 Vt[128 * 40];   // transposed V: [d][key], stride 40 (80B)
  __shared__ __align__(16) __bf16 Pl[4][16 * 40]; // per-wave P tile, stride 40 (80B)
  int tid = threadIdx.x, w = tid >> 6, lane = tid & 63;
  int bid = blockIdx.x;
  int qt = bid & 31, h = (bid >> 5) & 15, b = bid >> 9;
  int qs = qt * 64;
  int kvh = h >> 2;
  const __bf16* Qb = Qf + ((size_t)(b * NHQ + h) * TSEQ) * HDIM;
  const __bf16* Kb = Kf + ((size_t)(b * NKVH + kvh) * TSEQ) * HDIM;
  const __bf16* Vb = Vf + ((size_t)(b * NKVH + kvh) * TSEQ) * HDIM;

  // Q fragments (held for whole kernel)
  s16x8 aq[4];
  int qrow_f = qs + w * 16 + (lane & 15);
#pragma unroll
  for (int kb = 0; kb < 4; kb++)
    aq[kb] = *(const s16x8*)(Qb + (size_t)qrow_f * HDIM + kb * 32 + (lane >> 4) * 8);

  f32x4 acc[8];
  f32x4 zero = {0.f, 0.f, 0.f, 0.f};
#pragma unroll
  for (int db = 0; db < 8; db++) acc[db] = zero;
  float mrow[4], lrow[4];
#pragma unroll
  for (int r = 0; r < 4; r++) { mrow[r] = -1e30f; lrow[r] = 0.f; }

  int lo = qs - (WINSZ - 1);
  if (lo < 0) lo = 0;
  lo &= ~31;

  for (int ks = lo; ks <= qs + 63; ks += 32) {
    __syncthreads();
    // stage K (row-major, padded) and V (transposed)
#pragma unroll
    for (int i = 0; i < 2; i++) {
      int c = tid + 256 * i;
      int j = c >> 4, dk = (c & 15) * 8;
      int4 kv = *(const int4*)(Kb + (size_t)(ks + j) * HDIM + dk);
      *(int4*)&Kl[j * 136 + dk] = kv;
      int jv = c & 31, d0 = (c >> 5) * 8;
      int4 vv = *(const int4*)(Vb + (size_t)(ks + jv) * HDIM + d0);
      const __bf16* pv = (const __bf16*)&vv;
#pragma unroll
      for (int e = 0; e < 8; e++) Vt[(d0 + e) * 40 + jv] = pv[e];
    }
    __syncthreads();

    // S = Q K^T  (16 x 32 per wave)
    f32x4 sacc[2];
    sacc[0] = zero; sacc[1] = zero;
#pragma unroll
    for (int jb = 0; jb < 2; jb++)
#pragma unroll
      for (int kb = 0; kb < 4; kb++) {
        s16x8 bk = *(const s16x8*)&Kl[(jb * 16 + (lane & 15)) * 136 + kb * 32 + (lane >> 4) * 8];
        sacc[jb] = mfma16(aq[kb], bk, sacc[jb]);
      }

    // online softmax
    int colbase = ks + (lane & 15);
    float p0v[4], p1v[4], scf[4];
#pragma unroll
    for (int r = 0; r < 4; r++) {
      int qrow = qs + w * 16 + (lane >> 4) * 4 + r;
      float s0 = sacc[0][r] * ATTN_SCALE, s1 = sacc[1][r] * ATTN_SCALE;
      int j0 = colbase, j1 = colbase + 16;
      bool a0 = (j0 <= qrow) && (j0 > qrow - WINSZ);
      bool a1 = (j1 <= qrow) && (j1 > qrow - WINSZ);
      float mt = fmaxf(a0 ? s0 : -1e30f, a1 ? s1 : -1e30f);
#pragma unroll
      for (int off = 1; off < 16; off <<= 1) mt = fmaxf(mt, __shfl_xor(mt, off));
      float mn = fmaxf(mrow[r], mt);
      float p0 = a0 ? __expf(s0 - mn) : 0.f;
      float p1 = a1 ? __expf(s1 - mn) : 0.f;
      float sf = __expf(mrow[r] - mn);
      float ts = p0 + p1;
#pragma unroll
      for (int off = 1; off < 16; off <<= 1) ts += __shfl_xor(ts, off);
      lrow[r] = lrow[r] * sf + ts;
      mrow[r] = mn;
      p0v[r] = p0; p1v[r] = p1; scf[r] = sf;
    }

    // P -> LDS (per-wave), rescale accumulators
#pragma unroll
    for (int r = 0; r < 4; r++) {
      Pl[w][((lane >> 4) * 4 + r) * 40 + 0 * 16 + (lane & 15)] = (__bf16)p0v[r];
      Pl[w][((lane >> 4) * 4 + r) * 40 + 1 * 16 + (lane & 15)] = (__bf16)p1v[r];
    }
#pragma unroll
    for (int db = 0; db < 8; db++) {
      f32x4 t = acc[db];
#pragma unroll
      for (int r = 0; r < 4; r++) t[r] *= scf[r];
      acc[db] = t;
    }

    // PV
    s16x8 pa = *(const s16x8*)&Pl[w][(lane & 15) * 40 + (lane >> 4) * 8];
#pragma unroll
    for (int db = 0; db < 8; db++) {
      s16x8 bv = *(const s16x8*)&Vt[(db * 16 + (lane & 15)) * 40 + (lane >> 4) * 8];
      acc[db] = mfma16(pa, bv, acc[db]);
    }
  }

  // epilogue: divide by softmax denom, store bf16 to Ab [B*T][NH*D]
#pragma unroll
  for (int db = 0; db < 8; db++)
#pragma unroll
    for (int r = 0; r < 4; r++) {
      int qrow = qs + w * 16 + (lane >> 4) * 4 + r;
      float v = acc[db][r] / lrow[r];
      Ab[((size_t)(b * TSEQ + qrow)) * 2048 + h * HDIM + db * 16 + (lane & 15)] = (__bf16)v;
    }
}

extern "C" void kernel_launch(void* const* d_in, const int* in_sizes, int n_in,
                              void* d_out, int out_size, void* d_ws, size_t ws_size,
                              hipStream_t stream) {
  const float* x = (const float*)d_in[0];
  const float* wq = (const float*)d_in[1];
  const float* wk = (const float*)d_in[2];
  const float* wv = (const float*)d_in[3];
  const float* wo = (const float*)d_in[4];
  float* out = (float*)d_out;

  char* ws = (char*)d_ws;
  size_t off = 0;
  auto alloc = [&](size_t bytes) -> void* {
    void* p = ws + off;
    off += (bytes + 255) & ~(size_t)255;
    return p;
  };
  __bf16* Xb = (__bf16*)alloc((size_t)4096 * 2048 * 2);
  __bf16* Wqkvt = (__bf16*)alloc((size_t)3072 * 2048 * 2);
  __bf16* Wot = (__bf16*)alloc((size_t)2048 * 2048 * 2);
  __bf16* Q = (__bf16*)alloc((size_t)2 * NHQ * TSEQ * HDIM * 2);
  __bf16* Kb = (__bf16*)alloc((size_t)2 * NKVH * TSEQ * HDIM * 2);
  __bf16* Vb = (__bf16*)alloc((size_t)2 * NKVH * TSEQ * HDIM * 2);
  float* cosT = (float*)alloc((size_t)TSEQ * 64 * 4);
  float* sinT = (float*)alloc((size_t)TSEQ * 64 * 4);
  __bf16* Ab = Xb;  // alias: Xb dead after GEMM1

  rope_tables_kernel<<<TSEQ * 64 / 256, 256, 0, stream>>>(cosT, sinT);
  cast_kernel<<<8192, 256, 0, stream>>>(x, Xb, 2097152);
  dim3 tb(32, 8);
  transpose_cast<<<dim3(64, 64), tb, 0, stream>>>(wq, Wqkvt, 2048, 2048);
  transpose_cast<<<dim3(16, 64), tb, 0, stream>>>(wk, Wqkvt + (size_t)2048 * 2048, 2048, 512);
  transpose_cast<<<dim3(16, 64), tb, 0, stream>>>(wv, Wqkvt + (size_t)2560 * 2048, 2048, 512);
  transpose_cast<<<dim3(64, 64), tb, 0, stream>>>(wo, Wot, 2048, 2048);

  gemm256<1><<<dim3(12, 16), 512, 0, stream>>>(Xb, Wqkvt, nullptr, Q, Kb, Vb, 4096, 3072, 2048);
  normrope<<<4096 * 5, 256, 0, stream>>>(Q, Kb, cosT, sinT);
  attn_kernel<<<2 * NHQ * (TSEQ / 64), 256, 0, stream>>>(Q, Kb, Vb, Ab);
  gemm256<0><<<dim3(8, 16), 512, 0, stream>>>(Ab, Wot, out, nullptr, nullptr, nullptr, 4096, 2048,
                                              2048);
}

// Round 3
// 222.061 us; speedup vs baseline: 1.0827x; 1.0827x over previous
//
#include <hip/hip_runtime.h>
#include <hip/hip_bf16.h>
#include <cstdint>

#define NHQ 16
#define NKVH 4
#define HDIM 128
#define WINSZ 512
#define TSEQ 2048
#define ATTN_SCALE 0.08838834764831845f

typedef __attribute__((ext_vector_type(8))) short s16x8;
typedef __attribute__((ext_vector_type(4))) float f32x4;

__device__ __forceinline__ void gload16(const void* g, void* lds) {
  __builtin_amdgcn_global_load_lds(
      (const __attribute__((address_space(1))) unsigned int*)g,
      (__attribute__((address_space(3))) unsigned int*)(uintptr_t)lds,
      16, 0, 0);
}

__device__ __forceinline__ f32x4 mfma16(s16x8 a, s16x8 b, f32x4 c) {
  return __builtin_amdgcn_mfma_f32_16x16x32_bf16(a, b, c, 0, 0, 0);
}

#define SBAR() asm volatile("s_barrier" ::: "memory")
#define VMCNT(n) asm volatile("s_waitcnt vmcnt(" #n ")" ::: "memory")

template <int N>
__device__ __forceinline__ void vmwait() {
  if constexpr (N == 8) VMCNT(8);
  else if constexpr (N == 6) VMCNT(6);
  else if constexpr (N == 4) VMCNT(4);
  else if constexpr (N == 3) VMCNT(3);
  else VMCNT(0);
}

// ---------------- rope tables ----------------
__global__ __launch_bounds__(256) void rope_tables_kernel(float* __restrict__ cosT,
                                                          float* __restrict__ sinT) {
  int idx = blockIdx.x * 256 + threadIdx.x;   // t*64 + d2
  int t = idx >> 6, d2 = idx & 63;
  float inv = powf(10000.0f, -(float)d2 / 64.0f);
  float a = (float)t * inv;
  cosT[idx] = cosf(a);
  sinT[idx] = sinf(a);
}

// ---------------- f32 -> bf16 cast ----------------
__global__ __launch_bounds__(256) void cast_kernel(const float* __restrict__ in,
                                                   __bf16* __restrict__ out, int n4) {
  int i = blockIdx.x * 256 + threadIdx.x;
  if (i >= n4) return;
  float4 v = ((const float4*)in)[i];
  union { __bf16 h[4]; uint2 u; } pk;
  pk.h[0] = (__bf16)v.x; pk.h[1] = (__bf16)v.y; pk.h[2] = (__bf16)v.z; pk.h[3] = (__bf16)v.w;
  ((uint2*)out)[i] = pk.u;
}

// ---------------- transpose + cast: in f32 [R][C] -> out bf16 [C][R] ----------------
__global__ __launch_bounds__(256) void transpose_cast(const float* __restrict__ in,
                                                      __bf16* __restrict__ out, int R, int C) {
  __shared__ float tile[32][33];
  int c0 = blockIdx.x * 32, r0 = blockIdx.y * 32;
  int tx = threadIdx.x, ty = threadIdx.y;  // 32 x 8
#pragma unroll
  for (int i = 0; i < 4; i++)
    tile[ty + i * 8][tx] = in[(size_t)(r0 + ty + i * 8) * C + c0 + tx];
  __syncthreads();
#pragma unroll
  for (int i = 0; i < 4; i++)
    out[(size_t)(c0 + ty + i * 8) * R + r0 + tx] = (__bf16)tile[tx][ty + i * 8];
}

// ---------------- 256xBN phase-pipelined bt-GEMM ----------------
// A[M,K] bf16 row-major, Bt[N,K] bf16 row-major. BM=256, BN=NF*64, BK=32.
// 4 LDS buffers, stage 3 tiles ahead, counted vmcnt at tile boundary.
// MODE 0: C = f32 [M,N] row-major.  MODE 1: scatter bf16 into Q/K/V head-major.
template <int MODE, int NF>
__global__ __launch_bounds__(512, 2) void gemm256(const __bf16* __restrict__ A,
                                                  const __bf16* __restrict__ Bt,
                                                  float* __restrict__ Cf,
                                                  __bf16* __restrict__ Qo, __bf16* __restrict__ Ko,
                                                  __bf16* __restrict__ Vo, int M, int N, int K) {
  constexpr int BUNITS = NF / 2;            // 8KB stage units for B (128 rows each)
  constexpr int LPT = 2 + BUNITS;           // loads per tile per thread
  constexpr int STEADY = 2 * LPT;           // vmcnt at steady boundary
  // buffer: A-tile 2 units @0, B-tile BUNITS units @16384
  __shared__ __attribute__((aligned(16))) char Lds[4][(2 + BUNITS) * 8192];

  const int tid = threadIdx.x;
  const int w = tid >> 6, lane = tid & 63;
  const int wm = w >> 2, wn = w & 3;

  // bijective XCD-aware block swizzle (m204)
  const int nbx = gridDim.x;
  const int nwg = nbx * gridDim.y;
  const int bid = blockIdx.y * nbx + blockIdx.x;
  const int q8 = nwg >> 3, r8 = nwg & 7;
  const int xcd = bid & 7, idx = bid >> 3;
  const int swz = (xcd < r8 ? xcd * (q8 + 1) : r8 * (q8 + 1) + (xcd - r8) * q8) + idx;
  const int bx = swz % nbx, by = swz / nbx;
  const int m0 = by * 256, n0 = bx * (NF * 64);

  // staging: thread tid covers (row tid>>2, 16B chunk tid&3) of a 128-row unit.
  // LDS dest linear; global source inverse-swizzled (rule #21).
  const int r_st = tid >> 2;
  const int c_src = (tid & 3) ^ ((tid >> 3) & 3);
  const __bf16* gA = A + (size_t)(m0 + r_st) * K + c_src * 8;
  const __bf16* gB = Bt + (size_t)(n0 + r_st) * K + c_src * 8;
  const size_t hOF = (size_t)128 * K;  // unit = 128 rows

  auto stA = [&](int t, int h, int b) {
    gload16(gA + h * hOF + t * 32, Lds[b] + h * 8192 + w * 1024);
  };
  auto stB = [&](int t, int u, int b) {
    gload16(gB + u * hOF + t * 32, Lds[b] + 16384 + u * 8192 + w * 1024);
  };

  // fragment ds_read offsets (swizzled chunk = (lane>>4) ^ ((row>>1)&3))
  const int swzr = (((lane >> 4) ^ (((lane & 15) >> 1) & 3)) << 4);
  const int aoff = wm * 8192 + (lane & 15) * 64 + swzr;
  const int boff = (NF == 4 ? ((wn >> 1) * 8192 + (wn & 1) * 4096) : wn * 2048) +
                   (lane & 15) * 64 + swzr;

  f32x4 acc[8][NF];
  f32x4 zero = {0.f, 0.f, 0.f, 0.f};
#pragma unroll
  for (int i = 0; i < 8; i++)
#pragma unroll
    for (int j = 0; j < NF; j++) acc[i][j] = zero;

  const int NT = K >> 5;

  // prologue: stage tiles 0,1,2 into buffers 0,1,2; wait tile 0.
#pragma unroll
  for (int t = 0; t < 3; t++) {
    stA(t, 0, t); stA(t, 1, t);
#pragma unroll
    for (int u = 0; u < BUNITS; u++) stB(t, u, t);
  }
  vmwait<STEADY>();
  SBAR();

  for (int t = 0; t < NT; ++t) {
    const int cur = t & 3, nb = (t + 3) & 3;
    const bool more = (t + 3) < NT;
    const char* bA = Lds[cur];
    const char* bB = Lds[cur] + 16384;

    // ---- phase 0: B frags + A frags (mf 0-3); stage t+3: A0, A1 ----
    s16x8 fb[NF], fa[4];
#pragma unroll
    for (int nf = 0; nf < NF; nf++) fb[nf] = *(const s16x8*)(bB + boff + nf * 1024);
#pragma unroll
    for (int mf = 0; mf < 4; mf++) fa[mf] = *(const s16x8*)(bA + aoff + mf * 1024);
    if (more) { stA(t + 3, 0, nb); stA(t + 3, 1, nb); }
    SBAR();
    __builtin_amdgcn_s_setprio(1);
#pragma unroll
    for (int mf = 0; mf < 4; mf++)
#pragma unroll
      for (int nf = 0; nf < NF; nf++) acc[mf][nf] = mfma16(fa[mf], fb[nf], acc[mf][nf]);
    __builtin_amdgcn_s_setprio(0);
    SBAR();

    // ---- phase 1: A frags (mf 4-7); stage t+3: B units ----
#pragma unroll
    for (int mf = 0; mf < 4; mf++) fa[mf] = *(const s16x8*)(bA + aoff + 4096 + mf * 1024);
    if (more) {
#pragma unroll
      for (int u = 0; u < BUNITS; u++) stB(t + 3, u, nb);
    }
    SBAR();
    __builtin_amdgcn_s_setprio(1);
#pragma unroll
    for (int mf = 0; mf < 4; mf++)
#pragma unroll
      for (int nf = 0; nf < NF; nf++) acc[4 + mf][nf] = mfma16(fa[mf], fb[nf], acc[4 + mf][nf]);
    __builtin_amdgcn_s_setprio(0);

    // ---- tile boundary: counted vmcnt (t+1 must be resident; t+2,t+3 in flight) ----
    if (t < NT - 3) {
      vmwait<STEADY>();
      SBAR();
    } else if (t == NT - 3) {
      vmwait<LPT>();
      SBAR();
    } else if (t == NT - 2) {
      VMCNT(0);
      SBAR();
    }
  }

  // ---- epilogue ----
#pragma unroll
  for (int mf = 0; mf < 8; mf++)
#pragma unroll
    for (int nf = 0; nf < NF; nf++) {
      int rbase = m0 + wm * 128 + mf * 16 + (lane >> 4) * 4;
      int col = n0 + wn * (NF * 16) + nf * 16 + (lane & 15);
#pragma unroll
      for (int r = 0; r < 4; r++) {
        int m = rbase + r;
        float v = acc[mf][nf][r];
        if constexpr (MODE == 0) {
          Cf[(size_t)m * N + col] = v;
        } else {
          int b = m >> 11, t = m & 2047;
          __bf16 bv = (__bf16)v;
          if (col < 2048) {
            Qo[(((size_t)(b * NHQ + (col >> 7))) * TSEQ + t) * HDIM + (col & 127)] = bv;
          } else if (col < 2560) {
            int c2 = col - 2048;
            Ko[(((size_t)(b * NKVH + (c2 >> 7))) * TSEQ + t) * HDIM + (c2 & 127)] = bv;
          } else {
            int c2 = col - 2560;
            Vo[(((size_t)(b * NKVH + (c2 >> 7))) * TSEQ + t) * HDIM + (c2 & 127)] = bv;
          }
        }
      }
    }
}

// ---------------- in-place L2 norm + RoPE on Q and K (head-major) ----------------
__global__ __launch_bounds__(256) void normrope(__bf16* __restrict__ Q, __bf16* __restrict__ Kk,
                                                const float* __restrict__ cosT,
                                                const float* __restrict__ sinT) {
  int w = threadIdx.x >> 6, lane = threadIdx.x & 63;
  int row = blockIdx.x / 5;            // b*T + t
  int slot = (blockIdx.x % 5) * 4 + w; // 0..15 Q heads, 16..19 K heads
  int b = row >> 11, t = row & 2047;
  __bf16* p;
  if (slot < 16)
    p = Q + (((size_t)(b * NHQ + slot)) * TSEQ + t) * HDIM;
  else
    p = Kk + (((size_t)(b * NKVH + (slot - 16))) * TSEQ + t) * HDIM;
  float x1 = (float)p[lane], x2 = (float)p[lane + 64];
  float ss = x1 * x1 + x2 * x2;
#pragma unroll
  for (int off = 32; off; off >>= 1) ss += __shfl_xor(ss, off);
  float inv = 1.0f / fmaxf(sqrtf(ss), 1e-12f);
  x1 *= inv;
  x2 *= inv;
  float c = cosT[t * 64 + lane], s = sinT[t * 64 + lane];
  p[lane] = (__bf16)(x1 * c - x2 * s);
  p[lane + 64] = (__bf16)(x2 * c + x1 * s);
}

// ---------------- sliding-window flash attention ----------------
// grid: b*NHQ*(T/64); block 256 (4 waves x 16 q-rows). KV tile = 32.
__global__ __launch_bounds__(256) void attn_kernel(const __bf16* __restrict__ Qf,
                                                   const __bf16* __restrict__ Kf,
                                                   const __bf16* __restrict__ Vf,
                                                   __bf16* __restrict__ Ab) {
  __shared__ __align__(16) __bf16 Kl[32 * 136];   // padded: row stride 136 elems (272B)
  __shared__ __align__(16) __bf16 Vt[128 * 40];   // transposed V: [d][key], stride 40 (80B)
  __shared__ __align__(16) __bf16 Pl[4][16 * 40]; // per-wave P tile, stride 40 (80B)
  int tid = threadIdx.x, w = tid >> 6, lane = tid & 63;
  int bid = blockIdx.x;
  int qt = bid & 31, h = (bid >> 5) & 15, b = bid >> 9;
  int qs = qt * 64;
  int kvh = h >> 2;
  const __bf16* Qb = Qf + ((size_t)(b * NHQ + h) * TSEQ) * HDIM;
  const __bf16* Kb = Kf + ((size_t)(b * NKVH + kvh) * TSEQ) * HDIM;
  const __bf16* Vb = Vf + ((size_t)(b * NKVH + kvh) * TSEQ) * HDIM;

  // Q fragments (held for whole kernel)
  s16x8 aq[4];
  int qrow_f = qs + w * 16 + (lane & 15);
#pragma unroll
  for (int kb = 0; kb < 4; kb++)
    aq[kb] = *(const s16x8*)(Qb + (size_t)qrow_f * HDIM + kb * 32 + (lane >> 4) * 8);

  f32x4 acc[8];
  f32x4 zero = {0.f, 0.f, 0.f, 0.f};
#pragma unroll
  for (int db = 0; db < 8; db++) acc[db] = zero;
  float mrow[4], lrow[4];
#pragma unroll
  for (int r = 0; r < 4; r++) { mrow[r] = -1e30f; lrow[r] = 0.f; }

  int lo = qs - (WINSZ - 1);
  if (lo < 0) lo = 0;
  lo &= ~31;

  for (int ks = lo; ks <= qs + 63; ks += 32) {
    __syncthreads();
    // stage K (row-major, padded) and V (transposed)
#pragma unroll
    for (int i = 0; i < 2; i++) {
      int c = tid + 256 * i;
      int j = c >> 4, dk = (c & 15) * 8;
      int4 kv = *(const int4*)(Kb + (size_t)(ks + j) * HDIM + dk);
      *(int4*)&Kl[j * 136 + dk] = kv;
      int jv = c & 31, d0 = (c >> 5) * 8;
      int4 vv = *(const int4*)(Vb + (size_t)(ks + jv) * HDIM + d0);
      const __bf16* pv = (const __bf16*)&vv;
#pragma unroll
      for (int e = 0; e < 8; e++) Vt[(d0 + e) * 40 + jv] = pv[e];
    }
    __syncthreads();

    // S = Q K^T  (16 x 32 per wave)
    f32x4 sacc[2];
    sacc[0] = zero; sacc[1] = zero;
#pragma unroll
    for (int jb = 0; jb < 2; jb++)
#pragma unroll
      for (int kb = 0; kb < 4; kb++) {
        s16x8 bk = *(const s16x8*)&Kl[(jb * 16 + (lane & 15)) * 136 + kb * 32 + (lane >> 4) * 8];
        sacc[jb] = mfma16(aq[kb], bk, sacc[jb]);
      }

    // online softmax
    int colbase = ks + (lane & 15);
    float p0v[4], p1v[4], scf[4];
#pragma unroll
    for (int r = 0; r < 4; r++) {
      int qrow = qs + w * 16 + (lane >> 4) * 4 + r;
      float s0 = sacc[0][r] * ATTN_SCALE, s1 = sacc[1][r] * ATTN_SCALE;
      int j0 = colbase, j1 = colbase + 16;
      bool a0 = (j0 <= qrow) && (j0 > qrow - WINSZ);
      bool a1 = (j1 <= qrow) && (j1 > qrow - WINSZ);
      float mt = fmaxf(a0 ? s0 : -1e30f, a1 ? s1 : -1e30f);
#pragma unroll
      for (int off = 1; off < 16; off <<= 1) mt = fmaxf(mt, __shfl_xor(mt, off));
      float mn = fmaxf(mrow[r], mt);
      float p0 = a0 ? __expf(s0 - mn) : 0.f;
      float p1 = a1 ? __expf(s1 - mn) : 0.f;
      float sf = __expf(mrow[r] - mn);
      float ts = p0 + p1;
#pragma unroll
      for (int off = 1; off < 16; off <<= 1) ts += __shfl_xor(ts, off);
      lrow[r] = lrow[r] * sf + ts;
      mrow[r] = mn;
      p0v[r] = p0; p1v[r] = p1; scf[r] = sf;
    }

    // P -> LDS (per-wave), rescale accumulators
#pragma unroll
    for (int r = 0; r < 4; r++) {
      Pl[w][((lane >> 4) * 4 + r) * 40 + 0 * 16 + (lane & 15)] = (__bf16)p0v[r];
      Pl[w][((lane >> 4) * 4 + r) * 40 + 1 * 16 + (lane & 15)] = (__bf16)p1v[r];
    }
#pragma unroll
    for (int db = 0; db < 8; db++) {
      f32x4 t = acc[db];
#pragma unroll
      for (int r = 0; r < 4; r++) t[r] *= scf[r];
      acc[db] = t;
    }

    // PV
    s16x8 pa = *(const s16x8*)&Pl[w][(lane & 15) * 40 + (lane >> 4) * 8];
#pragma unroll
    for (int db = 0; db < 8; db++) {
      s16x8 bv = *(const s16x8*)&Vt[(db * 16 + (lane & 15)) * 40 + (lane >> 4) * 8];
      acc[db] = mfma16(pa, bv, acc[db]);
    }
  }

  // epilogue: divide by softmax denom, store bf16 to Ab [B*T][NH*D]
#pragma unroll
  for (int db = 0; db < 8; db++)
#pragma unroll
    for (int r = 0; r < 4; r++) {
      int qrow = qs + w * 16 + (lane >> 4) * 4 + r;
      float v = acc[db][r] / lrow[r];
      Ab[((size_t)(b * TSEQ + qrow)) * 2048 + h * HDIM + db * 16 + (lane & 15)] = (__bf16)v;
    }
}

extern "C" void kernel_launch(void* const* d_in, const int* in_sizes, int n_in,
                              void* d_out, int out_size, void* d_ws, size_t ws_size,
                              hipStream_t stream) {
  const float* x = (const float*)d_in[0];
  const float* wq = (const float*)d_in[1];
  const float* wk = (const float*)d_in[2];
  const float* wv = (const float*)d_in[3];
  const float* wo = (const float*)d_in[4];
  float* out = (float*)d_out;

  char* ws = (char*)d_ws;
  size_t off = 0;
  auto alloc = [&](size_t bytes) -> void* {
    void* p = ws + off;
    off += (bytes + 255) & ~(size_t)255;
    return p;
  };
  __bf16* Xb = (__bf16*)alloc((size_t)4096 * 2048 * 2);
  __bf16* Wqkvt = (__bf16*)alloc((size_t)3072 * 2048 * 2);
  __bf16* Wot = (__bf16*)alloc((size_t)2048 * 2048 * 2);
  __bf16* Q = (__bf16*)alloc((size_t)2 * NHQ * TSEQ * HDIM * 2);
  __bf16* Kb = (__bf16*)alloc((size_t)2 * NKVH * TSEQ * HDIM * 2);
  __bf16* Vb = (__bf16*)alloc((size_t)2 * NKVH * TSEQ * HDIM * 2);
  float* cosT = (float*)alloc((size_t)TSEQ * 64 * 4);
  float* sinT = (float*)alloc((size_t)TSEQ * 64 * 4);
  __bf16* Ab = Xb;  // alias: Xb dead after GEMM1

  rope_tables_kernel<<<TSEQ * 64 / 256, 256, 0, stream>>>(cosT, sinT);
  cast_kernel<<<8192, 256, 0, stream>>>(x, Xb, 2097152);
  dim3 tb(32, 8);
  transpose_cast<<<dim3(64, 64), tb, 0, stream>>>(wq, Wqkvt, 2048, 2048);
  transpose_cast<<<dim3(16, 64), tb, 0, stream>>>(wk, Wqkvt + (size_t)2048 * 2048, 2048, 512);
  transpose_cast<<<dim3(16, 64), tb, 0, stream>>>(wv, Wqkvt + (size_t)2560 * 2048, 2048, 512);
  transpose_cast<<<dim3(64, 64), tb, 0, stream>>>(wo, Wot, 2048, 2048);

  gemm256<1, 4><<<dim3(12, 16), 512, 0, stream>>>(Xb, Wqkvt, nullptr, Q, Kb, Vb, 4096, 3072, 2048);
  normrope<<<4096 * 5, 256, 0, stream>>>(Q, Kb, cosT, sinT);
  attn_kernel<<<2 * NHQ * (TSEQ / 64), 256, 0, stream>>>(Q, Kb, Vb, Ab);
  gemm256<0, 2><<<dim3(16, 16), 512, 0, stream>>>(Ab, Wot, out, nullptr, nullptr, nullptr, 4096,
                                                  2048, 2048);
}